// Round 9
// baseline (209.933 us; speedup 1.0000x reference)
//
#include <hip/hip_runtime.h>
#include <math.h>

#define BB   16
#define TT   1026
#define LEN  1024
#define NTOT (BB*LEN)        // 16384
#define NX   (BB*TT*64)      // 1050624 floats in x
#define AP   68              // LDS act row stride in shorts (measured ~conflict-free r4/r6/r7)

typedef __attribute__((ext_vector_type(8))) short bf16x8;
typedef __attribute__((ext_vector_type(4))) float f32x4;

// ---- ws byte offsets ----
#define OXH   ((size_t)0)                     // XH: NX shorts
#define OXL   (OXH + (size_t)NX*2)            // XL: NX shorts
#define OW1H  (OXL + (size_t)NX*2)            // 64 l * 8192 shorts (16 frags * 64 lanes * 8)
#define OW1L  (OW1H + (size_t)64*8192*2)
#define OW2H  (OW1L + (size_t)64*8192*2)      // 64 l * 4096 shorts (8 frags)
#define OW2L  (OW2H + (size_t)64*4096*2)
#define OVH   (OW2L + (size_t)64*4096*2)      // V = w1_last .* W2, fp32-split hi/lo
#define OVL   (OVH + (size_t)64*4096*2)
#define ORSV  (OVL + (size_t)64*4096*2)       // f32 [64*64]
#define OPD   (ORSV + (size_t)64*64*4)        // f32 [64][16384]  (dJ per l,n)

__device__ __forceinline__ unsigned int rne16(unsigned int u) {
    return (u + 0x7FFFu + ((u >> 16) & 1u)) >> 16;
}
__device__ __forceinline__ void split2(float v, short* h, short* s) {
    unsigned int u  = __float_as_uint(v);
    unsigned int hi = rne16(u);
    float lof = v - __uint_as_float(hi << 16);
    *h = (short)hi;
    *s = (short)rne16(__float_as_uint(lof));
}
// mask frag from sign bits of a1h frag: bf16 1.0 where positive else 0 (exact)
__device__ __forceinline__ bf16x8 maskfrag(bf16x8 a) {
    union { bf16x8 v; unsigned int u[4]; } A, M;
    A.v = a;
    #pragma unroll
    for (int j = 0; j < 4; ++j) {
        unsigned int t = (~A.u[j]) & 0x80008000u;   // sign==0 (positive) halves
        M.u[j] = (t >> 15) * 0x3F80u;               // -> bf16 1.0 per positive half
    }
    return M.v;
}

// ---- fused prep ----
// blocks [0,1026):    x -> XH/XL
// blocks [1026,1410): weight frags (384 blocks * 256 = 64 l * 1536 elems)
// blocks [1410,1474): per-l rowsumV
__global__ __launch_bounds__(256)
void prep_all(const float* __restrict__ x, const float* __restrict__ W1,
              const float* __restrict__ W2,
              short* __restrict__ XH, short* __restrict__ XL,
              short* __restrict__ W1H, short* __restrict__ W1L,
              short* __restrict__ W2H, short* __restrict__ W2L,
              short* __restrict__ VH,  short* __restrict__ VL,
              float* __restrict__ RSV)
{
    const int b = blockIdx.x, tid = threadIdx.x;
    if (b < 1026) {
        int i = (b * 256 + tid) * 4;
        float4 v = *(const float4*)(x + i);
        float vv[4] = {v.x, v.y, v.z, v.w};
        short hh[4], ll[4];
        #pragma unroll
        for (int j = 0; j < 4; ++j) split2(vv[j], &hh[j], &ll[j]);
        *(short4*)&XH[i] = make_short4(hh[0], hh[1], hh[2], hh[3]);
        *(short4*)&XL[i] = make_short4(ll[0], ll[1], ll[2], ll[3]);
    } else if (b < 1410) {
        int e = (b - 1026) * 256 + tid;          // 0..98303
        int l = e / 1536, r = e - l * 1536;
        if (r < 1024) {                           // W1 frag elem: fid = fk*4+nt
            int fid = r >> 6, lane = r & 63;
            int fk = fid >> 2, nt = fid & 3;
            int h  = nt * 16 + (lane & 15);
            int f0 = fk * 32 + (lane >> 4) * 8;
            const float* src = W1 + (size_t)l * 8256 + h * 129 + f0;
            size_t o = (size_t)l * 8192 + (size_t)r * 8;
            #pragma unroll
            for (int j = 0; j < 8; ++j) {
                short h_, l_; split2(src[j], &h_, &l_);
                W1H[o + j] = h_; W1L[o + j] = l_;
            }
        } else {                                  // W2 + V frag elem: fid = kc2*4+nt
            int r2 = r - 1024;
            int fid = r2 >> 6, lane = r2 & 63;
            int kc2 = fid >> 2, nt = fid & 3;
            int g  = nt * 16 + (lane & 15);
            int h0 = kc2 * 32 + (lane >> 4) * 8;
            const float* src = W2 + (size_t)l * 4096 + g * 64 + h0;
            size_t o = (size_t)l * 4096 + (size_t)r2 * 8;
            #pragma unroll
            for (int j = 0; j < 8; ++j) {
                float w2v  = src[j];
                float w1lv = W1[(size_t)l * 8256 + (h0 + j) * 129 + 128];
                short h_, l_;
                split2(w2v, &h_, &l_);        W2H[o + j] = h_; W2L[o + j] = l_;
                split2(w2v * w1lv, &h_, &l_); VH[o + j]  = h_; VL[o + j]  = l_;
            }
        }
    } else {
        const int l = b - 1410;
        if (tid < 64) {
            float s = 0.f;
            for (int h = 0; h < 64; ++h)
                s += W2[(size_t)l * 4096 + tid * 64 + h] * W1[(size_t)l * 8256 + h * 129 + 128];
            RSV[l * 64 + tid] = s;
        }
    }
}

// logdet[n] = sum_l log|PD[l][n]|
__global__ __launch_bounds__(256)
void finish_logdet(const float* __restrict__ PD, float* __restrict__ logdet) {
    int i = blockIdx.x * 256 + threadIdx.x;      // grid exact: NTOT
    float acc = 0.f;
    #pragma unroll 8
    for (int l = 0; l < 64; ++l)
        acc += __logf(fabsf(PD[(size_t)l * NTOT + i]));
    logdet[i] = acc;
}

__global__ __launch_bounds__(256, 2)
void np_main(const float* __restrict__ x,  const float* __restrict__ W1,
             const float* __restrict__ b1, const float* __restrict__ b2,
             const float* __restrict__ W3, const float* __restrict__ b3,
             const short* __restrict__ XH, const short* __restrict__ XL,
             const short* __restrict__ W1H, const short* __restrict__ W1L,
             const short* __restrict__ W2H, const short* __restrict__ W2L,
             const short* __restrict__ VH,  const short* __restrict__ VL,
             const float* __restrict__ RSV, float* __restrict__ PD,
             float* __restrict__ out)
{
    // Wave-private LDS, no __syncthreads. INVARIANT: wave wid touches ONLY
    // shorts [wid*64*AP, (wid+1)*64*AP) of each array; epilogue scratch at
    // (float*)base + wid*2176 lies exactly inside the wave's own 64 rows.
    __shared__ __align__(16) short a1h[256 * AP];
    __shared__ __align__(16) short a1l[256 * AP];

    // grid: blockIdx.x = n-tile (fast), blockIdx.y = l
    // -> consecutive blocks share l => weight frags stay L1/L2-hot.
    const int l = blockIdx.y, tid = threadIdx.x;
    const int nb = blockIdx.x * 256;
    const int bb = nb >> 10, t0 = nb & 1023;
    const int lane = tid & 63, wid = tid >> 6;
    const int q = lane >> 4, c16 = lane & 15;
    const int wrow = wid * 64;
    const size_t xrow0 = (size_t)(bb * TT + t0);

    // ---- stage 1: z1[64rows x 64h] = x_lags @ W1' (K=128, 3-pass split) ----
    f32x4 z1[4][4];
    #pragma unroll
    for (int mt = 0; mt < 4; ++mt)
        #pragma unroll
        for (int nt = 0; nt < 4; ++nt) z1[mt][nt] = (f32x4){0.f, 0.f, 0.f, 0.f};

    const short* w1hb = W1H + (size_t)l * 8192;
    const short* w1lb = W1L + (size_t)l * 8192;
    #pragma unroll
    for (int fk = 0; fk < 4; ++fk) {
        const int colx = (fk & 1) * 32 + q * 8;
        const int rofs = fk >> 1;
        bf16x8 ah[4], al[4], bh[4], bl[4];
        #pragma unroll
        for (int mt = 0; mt < 4; ++mt) {
            size_t xo = (xrow0 + wrow + mt * 16 + c16 + rofs) * 64 + colx;
            ah[mt] = *(const bf16x8*)(XH + xo);
            al[mt] = *(const bf16x8*)(XL + xo);
        }
        #pragma unroll
        for (int nt = 0; nt < 4; ++nt) {
            size_t wo = (size_t)((fk * 4 + nt) * 64 + lane) * 8;
            bh[nt] = *(const bf16x8*)(w1hb + wo);
            bl[nt] = *(const bf16x8*)(w1lb + wo);
        }
        #pragma unroll
        for (int mt = 0; mt < 4; ++mt)
            #pragma unroll
            for (int nt = 0; nt < 4; ++nt) {
                z1[mt][nt] = __builtin_amdgcn_mfma_f32_16x16x32_bf16(ah[mt], bh[nt], z1[mt][nt], 0, 0, 0);
                z1[mt][nt] = __builtin_amdgcn_mfma_f32_16x16x32_bf16(al[mt], bh[nt], z1[mt][nt], 0, 0, 0);
                z1[mt][nt] = __builtin_amdgcn_mfma_f32_16x16x32_bf16(ah[mt], bl[nt], z1[mt][nt], 0, 0, 0);
            }
    }

    // finalize z1 fp32: + x_t*w1_last + b1 ; write a1 hi/lo
    // cheap split: trunc-hi + RNE-lo (sum error ~2^-17; sign/mask preserved)
    float w1lc[4], b1c[4];
    #pragma unroll
    for (int nt = 0; nt < 4; ++nt) {
        w1lc[nt] = W1[(size_t)(l * 64 + nt * 16 + c16) * 129 + 128];
        b1c[nt]  = b1[l * 64 + nt * 16 + c16];
    }
    #pragma unroll
    for (int mt = 0; mt < 4; ++mt)
        #pragma unroll
        for (int r = 0; r < 4; ++r) {
            int mrow = wrow + mt * 16 + q * 4 + r;
            float xt = x[(xrow0 + mrow + 2) * 64 + l];
            #pragma unroll
            for (int nt = 0; nt < 4; ++nt) {
                float z  = z1[mt][nt][r] + xt * w1lc[nt] + b1c[nt];
                float av = z > 0.f ? z : 0.01f * z;
                int idx = mrow * AP + nt * 16 + c16;
                unsigned int u = __float_as_uint(av);
                a1h[idx] = (short)(u >> 16);
                float res = av - __uint_as_float(u & 0xFFFF0000u);
                a1l[idx] = (short)rne16(__float_as_uint(res));
            }
        }

    // ---- stage 2 (wave-private, no barrier):
    //   z2a = a1 @ W2'   (3-pass: ah*Wh + al*Wh + ah*Wl) — full precision (d2 mask)
    //   z2m = mask @ V'  (2-pass: mf*Vh + mf*Vl) — mask exact, V fp32-split => ~2^-17
    f32x4 z2a[4][4], z2m[4][4];
    #pragma unroll
    for (int mt = 0; mt < 4; ++mt)
        #pragma unroll
        for (int nt = 0; nt < 4; ++nt) {
            z2a[mt][nt] = (f32x4){0.f, 0.f, 0.f, 0.f};
            z2m[mt][nt] = (f32x4){0.f, 0.f, 0.f, 0.f};
        }
    const short* w2hb = W2H + (size_t)l * 4096;
    const short* w2lb = W2L + (size_t)l * 4096;
    const short* vhb  = VH  + (size_t)l * 4096;
    const short* vlb  = VL  + (size_t)l * 4096;
    #pragma unroll
    for (int kc2 = 0; kc2 < 2; ++kc2) {
        bf16x8 ah2[4], al2[4];
        #pragma unroll
        for (int mt = 0; mt < 4; ++mt) {
            int ao = (wrow + mt * 16 + c16) * AP + kc2 * 32 + q * 8;
            ah2[mt] = *(const bf16x8*)&a1h[ao];
            al2[mt] = *(const bf16x8*)&a1l[ao];
        }
        {   // z2a block
            bf16x8 wh[4], wl2[4];
            #pragma unroll
            for (int nt = 0; nt < 4; ++nt) {
                size_t wo = (size_t)((kc2 * 4 + nt) * 64 + lane) * 8;
                wh[nt]  = *(const bf16x8*)(w2hb + wo);
                wl2[nt] = *(const bf16x8*)(w2lb + wo);
            }
            #pragma unroll
            for (int mt = 0; mt < 4; ++mt)
                #pragma unroll
                for (int nt = 0; nt < 4; ++nt) {
                    z2a[mt][nt] = __builtin_amdgcn_mfma_f32_16x16x32_bf16(ah2[mt], wh[nt],  z2a[mt][nt], 0, 0, 0);
                    z2a[mt][nt] = __builtin_amdgcn_mfma_f32_16x16x32_bf16(al2[mt], wh[nt],  z2a[mt][nt], 0, 0, 0);
                    z2a[mt][nt] = __builtin_amdgcn_mfma_f32_16x16x32_bf16(ah2[mt], wl2[nt], z2a[mt][nt], 0, 0, 0);
                }
        }
        {   // z2m block
            bf16x8 vh[4], vl[4];
            #pragma unroll
            for (int nt = 0; nt < 4; ++nt) {
                size_t wo = (size_t)((kc2 * 4 + nt) * 64 + lane) * 8;
                vh[nt] = *(const bf16x8*)(vhb + wo);
                vl[nt] = *(const bf16x8*)(vlb + wo);
            }
            #pragma unroll
            for (int mt = 0; mt < 4; ++mt) {
                bf16x8 mf = maskfrag(ah2[mt]);
                #pragma unroll
                for (int nt = 0; nt < 4; ++nt) {
                    z2m[mt][nt] = __builtin_amdgcn_mfma_f32_16x16x32_bf16(mf, vh[nt], z2m[mt][nt], 0, 0, 0);
                    z2m[mt][nt] = __builtin_amdgcn_mfma_f32_16x16x32_bf16(mf, vl[nt], z2m[mt][nt], 0, 0, 0);
                }
            }
        }
    }

    // ---- epilogue: per-row dot with w3, via wave-private LDS transpose ----
    float b2c[4], w3c[4], rsv[4];
    #pragma unroll
    for (int nt = 0; nt < 4; ++nt) {
        int g = nt * 16 + c16;
        b2c[nt] = b2[l * 64 + g];
        w3c[nt] = W3[l * 64 + g];
        rsv[nt] = RSV[l * 64 + g];
    }
    float* spo = (float*)a1h + wid * 2176;   // wave's own quarter (2176 floats)
    float* spd = (float*)a1l + wid * 2176;
    #pragma unroll
    for (int mt = 0; mt < 4; ++mt)
        #pragma unroll
        for (int r = 0; r < 4; ++r) {
            float po = 0.f, pd = 0.f;
            #pragma unroll
            for (int nt = 0; nt < 4; ++nt) {
                float z  = z2a[mt][nt][r] + b2c[nt];
                float a2 = z > 0.f ? z : 0.01f * z;
                float d2 = z > 0.f ? 1.0f : 0.01f;
                float zt = 0.01f * rsv[nt] + 0.99f * z2m[mt][nt][r];
                po += a2 * w3c[nt];
                pd += d2 * zt * w3c[nt];
            }
            int row = mt * 16 + q * 4 + r;   // 0..63
            spo[row * 17 + c16] = po;
            spd[row * 17 + c16] = pd;
        }
    __threadfence_block();

    {
        float so = 0.f, sd = 0.f;
        #pragma unroll
        for (int j = 0; j < 16; ++j) {
            so += spo[lane * 17 + j];
            sd += spd[lane * 17 + j];
        }
        int n = nb + wrow + lane;
        out[(size_t)n * 64 + l] = so + b3[l];
        PD[(size_t)l * NTOT + n] = sd;       // coalesced; log+sum in finish kernel
    }
}

extern "C" void kernel_launch(void* const* d_in, const int* in_sizes, int n_in,
                              void* d_out, int out_size, void* d_ws, size_t ws_size,
                              hipStream_t stream) {
    const float* x  = (const float*)d_in[0];
    const float* W1 = (const float*)d_in[1];
    const float* b1 = (const float*)d_in[2];
    const float* W2 = (const float*)d_in[3];
    const float* b2 = (const float*)d_in[4];
    const float* W3 = (const float*)d_in[5];
    const float* b3 = (const float*)d_in[6];
    float* out = (float*)d_out;
    char* ws = (char*)d_ws;

    short* XH   = (short*)(ws + OXH);
    short* XL   = (short*)(ws + OXL);
    short* W1Hp = (short*)(ws + OW1H);
    short* W1Lp = (short*)(ws + OW1L);
    short* W2Hp = (short*)(ws + OW2H);
    short* W2Lp = (short*)(ws + OW2L);
    short* VHp  = (short*)(ws + OVH);
    short* VLp  = (short*)(ws + OVL);
    float* RSVp = (float*)(ws + ORSV);
    float* PDp  = (float*)(ws + OPD);

    hipLaunchKernelGGL(prep_all, dim3(1026 + 384 + 64), dim3(256), 0, stream,
                       x, W1, W2, XH, XL, W1Hp, W1Lp, W2Hp, W2Lp, VHp, VLp, RSVp);
    dim3 grid(NTOT / 256 /*n tiles (fast dim)*/, 64 /*l*/);
    hipLaunchKernelGGL(np_main, grid, dim3(256), 0, stream,
                       x, W1, b1, b2, W3, b3,
                       XH, XL, W1Hp, W1Lp, W2Hp, W2Lp, VHp, VLp, RSVp, PDp, out);
    hipLaunchKernelGGL(finish_logdet, dim3(NTOT / 256), dim3(256), 0, stream,
                       PDp, out + (size_t)NTOT * 64);
}